// Round 9
// baseline (909.361 us; speedup 1.0000x reference)
//
#include <hip/hip_runtime.h>
#include <hip/hip_fp16.h>
#include <math.h>

#define FIN 512
#define FH 16
#define FOUT 40
#define DT 448           // dst nodes per tile (acc fits LDS with AP pad)
#define SUB 512          // src rows per staged subtile (16 KiB fp16)
#define SRC_BITS 17
#define SRC_MASK 0x1FFFF
#define BCHUNK 4096
#define HCHUNK 16384
#define NB_MAX 1024
#define AP 17            // padded acc row stride
#define NTS_MAX 200

typedef unsigned int u32;

// per-lane global 16B -> wave-linear LDS (no dest VGPR; vmcnt-tracked)
__device__ __forceinline__ void gload_lds16(const void* g, void* l) {
  __builtin_amdgcn_global_load_lds((const __attribute__((address_space(1))) u32*)g,
                                   (__attribute__((address_space(3))) u32*)l, 16, 0, 0);
}

// ---------- dst-tile histogram ----------
__global__ __launch_bounds__(256) void histA_k(const int* __restrict__ dst, int E, int NB,
                                               unsigned* __restrict__ bcnt) {
  __shared__ unsigned h[NB_MAX];
  for (int b = threadIdx.x; b < NB; b += 256) h[b] = 0;
  __syncthreads();
  const int base = blockIdx.x * HCHUNK;
  const int cn = min(HCHUNK, E - base);
  for (int u = threadIdx.x; u < cn; u += 256)
    atomicAdd(&h[((unsigned)dst[base + u]) / DT], 1u);
  __syncthreads();
  for (int b = threadIdx.x; b < NB; b += 256) {
    unsigned c = h[b];
    if (c) atomicAdd(&bcnt[b], c);
  }
}

// ---------- exclusive scan of tile counts ----------
__global__ __launch_bounds__(1024) void scanB_k(const unsigned* __restrict__ bcnt, int NB,
                                                unsigned* __restrict__ boff,
                                                unsigned* __restrict__ bcur) {
  __shared__ unsigned ws[16];
  const int t = threadIdx.x, lane = t & 63, wid = t >> 6;
  unsigned v = (t < NB) ? bcnt[t] : 0;
  unsigned incl = v;
#pragma unroll
  for (int d = 1; d < 64; d <<= 1) {
    unsigned o = __shfl_up(incl, d);
    if (lane >= d) incl += o;
  }
  if (lane == 63) ws[wid] = incl;
  __syncthreads();
  unsigned woff = 0, tot = 0;
#pragma unroll
  for (int w = 0; w < 16; ++w) {
    unsigned s = ws[w];
    if (w < wid) woff += s;
    tot += s;
  }
  unsigned ex = woff + incl - v;
  if (t < NB) { boff[t] = ex; bcur[t] = ex; }
  if (t == 0) boff[NB] = tot;
}

// ---------- bin edges by dst-tile (chunk-local counting sort) ----------
__global__ __launch_bounds__(256) void bin_k(const int* __restrict__ src,
                                             const int* __restrict__ dst, int E, int NB,
                                             unsigned* __restrict__ bcur,
                                             unsigned* __restrict__ bins) {
  __shared__ unsigned hist[NB_MAX];
  __shared__ unsigned excl[NB_MAX];
  __shared__ unsigned gbase[NB_MAX];
  __shared__ unsigned lcur[NB_MAX];
  __shared__ unsigned stage[BCHUNK];
  __shared__ unsigned short sbkt[BCHUNK];
  __shared__ unsigned wtot[4];
  const int t = threadIdx.x, lane = t & 63, wid = t >> 6;
  for (int b = t; b < NB; b += 256) hist[b] = 0;
  __syncthreads();
  const int base = blockIdx.x * BCHUNK;
  const int cn = min(BCHUNK, E - base);
  for (int u = t; u < cn; u += 256)
    atomicAdd(&hist[((unsigned)dst[base + u]) / DT], 1u);
  __syncthreads();
  unsigned loc[4], s = 0;
#pragma unroll
  for (int j = 0; j < 4; ++j) {
    int idx = t * 4 + j;
    loc[j] = s;
    s += (idx < NB) ? hist[idx] : 0;
  }
  unsigned incl = s;
#pragma unroll
  for (int d = 1; d < 64; d <<= 1) {
    unsigned o = __shfl_up(incl, d);
    if (lane >= d) incl += o;
  }
  if (lane == 63) wtot[wid] = incl;
  __syncthreads();
  unsigned woff = 0;
  for (int w = 0; w < wid; ++w) woff += wtot[w];
  unsigned tex = woff + incl - s;
#pragma unroll
  for (int j = 0; j < 4; ++j) {
    int idx = t * 4 + j;
    if (idx < NB) excl[idx] = tex + loc[j];
  }
  __syncthreads();
  for (int b = t; b < NB; b += 256) {
    unsigned c = hist[b];
    gbase[b] = c ? atomicAdd(&bcur[b], c) : 0u;
    lcur[b] = excl[b];
  }
  __syncthreads();
  for (int u = t; u < cn; u += 256) {
    int e = base + u;
    unsigned d = (unsigned)dst[e];
    unsigned bkt = d / DT;
    unsigned dloc = d - bkt * DT;
    unsigned pk = ((unsigned)src[e]) | (dloc << SRC_BITS);
    unsigned lr = atomicAdd(&lcur[bkt], 1u);
    stage[lr] = pk;
    sbkt[lr] = (unsigned short)bkt;
  }
  __syncthreads();
  for (int u = t; u < cn; u += 256) {
    unsigned bkt = sbkt[u];
    bins[gbase[bkt] + (u - excl[bkt])] = stage[u];
  }
}

// ---------- per-node degree -> dinv ----------
__global__ __launch_bounds__(512) void deg_k(const unsigned* __restrict__ boff,
                                             const unsigned* __restrict__ bins, int n,
                                             float* __restrict__ dinv) {
  __shared__ unsigned dh[DT];
  const int t = threadIdx.x, b = blockIdx.x;
  if (t < DT) dh[t] = 0;
  __syncthreads();
  const unsigned jb = boff[b], je = boff[b + 1];
  for (unsigned j = jb + t; j < je; j += 512) atomicAdd(&dh[bins[j] >> SRC_BITS], 1u);
  __syncthreads();
  const int i = b * DT + t;
  if (t < DT && i < n) dinv[i] = rsqrtf((float)dh[t] + 1.0f);
}

// ---------- per dst-tile: sort edges by src-subtile ----------
__global__ __launch_bounds__(1024) void bin2_k(const unsigned* __restrict__ boff,
                                               const unsigned* __restrict__ bins, int nts,
                                               unsigned* __restrict__ out2,
                                               unsigned* __restrict__ off2) {
  __shared__ unsigned h2[NTS_MAX];
  __shared__ unsigned o2[NTS_MAX + 1];
  __shared__ unsigned cur2[NTS_MAX];
  const int t = threadIdx.x, b = blockIdx.x;
  const unsigned jb = boff[b], je = boff[b + 1];
  if (t < nts) h2[t] = 0;
  __syncthreads();
  for (unsigned j = jb + t; j < je; j += 1024)
    atomicAdd(&h2[(bins[j] & SRC_MASK) >> 9], 1u);
  __syncthreads();
  if (t == 0) {
    unsigned s = 0;
    for (int i = 0; i < nts; ++i) { o2[i] = s; s += h2[i]; }
    o2[nts] = s;
  }
  __syncthreads();
  if (t < nts) cur2[t] = o2[t];
  if (t <= nts) off2[(size_t)b * (nts + 1) + t] = o2[t];
  __syncthreads();
  for (unsigned j = jb + t; j < je; j += 1024) {
    const unsigned pk = bins[j];
    const unsigned srcf = pk & SRC_MASK;
    const unsigned st = srcf >> 9;
    const unsigned p = atomicAdd(&cur2[st], 1u);
    out2[jb + p] = (srcf & 511u) | ((pk >> SRC_BITS) << 9);
  }
}

// ---------------- hs1 = (x @ W1) * dinv[row], stored fp16 ----------------
__global__ __launch_bounds__(256) void gemm1_k(const float* __restrict__ x,
                                               const float* __restrict__ W1,
                                               const float* __restrict__ dinv, int n,
                                               __half* __restrict__ hs1) {
  __shared__ float w1s[FIN * FH];
  for (int idx = threadIdx.x; idx < FIN * FH; idx += 256) w1s[idx] = W1[idx];
  __syncthreads();
  const int row_raw = blockIdx.x * 256 + threadIdx.x;
  const int row = row_raw < n ? row_raw : n - 1;
  const float4* __restrict__ xr = (const float4*)(x + (size_t)row * FIN);
  float4 a0 = {0, 0, 0, 0}, a1 = {0, 0, 0, 0}, a2 = {0, 0, 0, 0}, a3 = {0, 0, 0, 0};
#pragma unroll 2
  for (int it = 0; it < FIN / 4; ++it) {
    float4 xv = xr[it];
    const float* wf = w1s + it * 4 * FH;
#pragma unroll
    for (int j = 0; j < 4; ++j) {
      const float xj = (j == 0) ? xv.x : (j == 1) ? xv.y : (j == 2) ? xv.z : xv.w;
      const float* wj = wf + j * FH;
      float4 w0 = *(const float4*)(wj + 0);
      float4 w1 = *(const float4*)(wj + 4);
      float4 w2 = *(const float4*)(wj + 8);
      float4 w3 = *(const float4*)(wj + 12);
      a0.x += xj * w0.x; a0.y += xj * w0.y; a0.z += xj * w0.z; a0.w += xj * w0.w;
      a1.x += xj * w1.x; a1.y += xj * w1.y; a1.z += xj * w1.z; a1.w += xj * w1.w;
      a2.x += xj * w2.x; a2.y += xj * w2.y; a2.z += xj * w2.z; a2.w += xj * w2.w;
      a3.x += xj * w3.x; a3.y += xj * w3.y; a3.z += xj * w3.z; a3.w += xj * w3.w;
    }
  }
  if (row_raw < n) {
    const float di = dinv[row];
    __half2 hb[8];
    hb[0] = __floats2half2_rn(a0.x * di, a0.y * di);
    hb[1] = __floats2half2_rn(a0.z * di, a0.w * di);
    hb[2] = __floats2half2_rn(a1.x * di, a1.y * di);
    hb[3] = __floats2half2_rn(a1.z * di, a1.w * di);
    hb[4] = __floats2half2_rn(a2.x * di, a2.y * di);
    hb[5] = __floats2half2_rn(a2.z * di, a2.w * di);
    hb[6] = __floats2half2_rn(a3.x * di, a3.y * di);
    hb[7] = __floats2half2_rn(a3.z * di, a3.w * di);
    uint4* o = (uint4*)(hs1 + (size_t)row * FH);
    o[0] = ((const uint4*)hb)[0];
    o[1] = ((const uint4*)hb)[1];
  }
}

// ---- accumulate one fp16 row (2x uint4) into padded LDS acc row ----
__device__ __forceinline__ void accum_row(float* __restrict__ arow, uint4 q0, uint4 q1) {
  float2 f;
  f = __half22float2(*(const __half2*)&q0.x); atomicAdd(arow + 0, f.x);  atomicAdd(arow + 1, f.y);
  f = __half22float2(*(const __half2*)&q0.y); atomicAdd(arow + 2, f.x);  atomicAdd(arow + 3, f.y);
  f = __half22float2(*(const __half2*)&q0.z); atomicAdd(arow + 4, f.x);  atomicAdd(arow + 5, f.y);
  f = __half22float2(*(const __half2*)&q0.w); atomicAdd(arow + 6, f.x);  atomicAdd(arow + 7, f.y);
  f = __half22float2(*(const __half2*)&q1.x); atomicAdd(arow + 8, f.x);  atomicAdd(arow + 9, f.y);
  f = __half22float2(*(const __half2*)&q1.y); atomicAdd(arow + 10, f.x); atomicAdd(arow + 11, f.y);
  f = __half22float2(*(const __half2*)&q1.z); atomicAdd(arow + 12, f.x); atomicAdd(arow + 13, f.y);
  f = __half22float2(*(const __half2*)&q1.w); atomicAdd(arow + 14, f.x); atomicAdd(arow + 15, f.y);
}

// stage one 512-row subtile (16 KiB) coalesced: 1024 threads x 16B
__device__ __forceinline__ void stage_sub(const __half* __restrict__ tab, int st,
                                          __half* __restrict__ buf, int t) {
  const __half* g = tab + ((size_t)st * SUB + (t >> 1)) * FH + (t & 1) * 8;
  gload_lds16(g, buf + t * 8);
}

// consume edges of one (tile, subtile) pair from LDS
__device__ __forceinline__ void consume_sub(const unsigned* __restrict__ out2, unsigned jb,
                                            unsigned a, unsigned e,
                                            const __half* __restrict__ buf,
                                            float* __restrict__ acc, int t) {
  for (unsigned j = a + t; j < e; j += 1024) {
    const unsigned pk = out2[jb + j];
    const int srcl = pk & 511, dstl = pk >> 9;
    const uint4 q0 = *(const uint4*)(buf + srcl * FH);
    const uint4 q1 = *(const uint4*)(buf + srcl * FH + 8);
    accum_row(acc + dstl * AP, q0, q1);
  }
}

// shared tile loop: fills acc[DT][AP] with sum of table rows over incoming edges
__device__ __forceinline__ void tile_gather(const __half* __restrict__ tab,
                                            const unsigned* __restrict__ out2,
                                            const unsigned* __restrict__ off2r,
                                            unsigned jb, int nts, int t,
                                            __half* __restrict__ sb0,
                                            __half* __restrict__ sb1,
                                            float* __restrict__ acc) {
  for (int u = t; u < DT * AP; u += 1024) acc[u] = 0.f;
  stage_sub(tab, 0, sb0, t);
  __syncthreads();  // acc zero visible; stage(0) drained (vmcnt0 implied)
  for (int st = 0; st < nts; ++st) {
    asm volatile("s_waitcnt vmcnt(0)" ::: "memory");  // stage(st) landed (this wave)
    __builtin_amdgcn_sched_barrier(0);
    __builtin_amdgcn_s_barrier();                     // all waves' stage(st) landed
    __builtin_amdgcn_sched_barrier(0);
    __half* cur = (st & 1) ? sb1 : sb0;
    __half* nxt = (st & 1) ? sb0 : sb1;
    if (st + 1 < nts) stage_sub(tab, st + 1, nxt, t); // overlaps consume
    consume_sub(out2, jb, off2r[st], off2r[st + 1], cur, acc, t);
    __builtin_amdgcn_sched_barrier(0);
    __builtin_amdgcn_s_barrier();                     // all consumed before overwrite
    __builtin_amdgcn_sched_barrier(0);
  }
  __syncthreads();
}

// ---------- layer-1: 2D-tiled gather + relu epilogue -> rs fp16 ----------
__global__ __launch_bounds__(1024) void gath1_k(const __half* __restrict__ hs1,
                                                const unsigned* __restrict__ boff,
                                                const unsigned* __restrict__ out2,
                                                const unsigned* __restrict__ off2, int nts,
                                                const float* __restrict__ dinv,
                                                const float* __restrict__ b1, int n,
                                                __half* __restrict__ rs) {
  __shared__ float acc[DT * AP];              // 30.5 KiB
  __shared__ __half sb0[SUB * FH];            // 16 KiB
  __shared__ __half sb1[SUB * FH];            // 16 KiB
  __shared__ float b1s[FH];
  const int t = threadIdx.x, b = blockIdx.x;
  if (t < FH) b1s[t] = b1[t];
  tile_gather(hs1, out2, off2 + (size_t)b * (nts + 1), boff[b], nts, t, sb0, sb1, acc);
  const int base = b * DT;
  for (int idx = t; idx < DT * 4; idx += 1024) {
    const int node = idx >> 2, sub = idx & 3;
    const int i = base + node;
    if (i < n) {
      const float* arow = acc + node * AP + sub * 4;
      const float a0 = arow[0], a1 = arow[1], a2 = arow[2], a3 = arow[3];
      const __half2* hp = (const __half2*)(hs1 + (size_t)i * FH + sub * 4);
      const float2 h0 = __half22float2(hp[0]);
      const float2 h1 = __half22float2(hp[1]);
      const float d = dinv[i];
      float r0 = (a0 + h0.x) * d + b1s[sub * 4 + 0];
      float r1 = (a1 + h0.y) * d + b1s[sub * 4 + 1];
      float r2 = (a2 + h1.x) * d + b1s[sub * 4 + 2];
      float r3 = (a3 + h1.y) * d + b1s[sub * 4 + 3];
      r0 = fmaxf(r0, 0.f) * d;
      r1 = fmaxf(r1, 0.f) * d;
      r2 = fmaxf(r2, 0.f) * d;
      r3 = fmaxf(r3, 0.f) * d;
      __half2* rp = (__half2*)(rs + (size_t)i * FH + sub * 4);
      rp[0] = __floats2half2_rn(r0, r1);
      rp[1] = __floats2half2_rn(r2, r3);
    }
  }
}

// ---------- layer-2: 2D-tiled gather + W2 matvec + log_softmax ----------
__global__ __launch_bounds__(1024) void gath2_k(const __half* __restrict__ rs,
                                                const unsigned* __restrict__ boff,
                                                const unsigned* __restrict__ out2,
                                                const unsigned* __restrict__ off2, int nts,
                                                const float* __restrict__ dinv,
                                                const float* __restrict__ W2,
                                                const float* __restrict__ b2, int n,
                                                float* __restrict__ out) {
  __shared__ float acc[DT * AP];
  __shared__ __half sb0[SUB * FH];
  __shared__ __half sb1[SUB * FH];
  const int t = threadIdx.x, b = blockIdx.x;
  tile_gather(rs, out2, off2 + (size_t)b * (nts + 1), boff[b], nts, t, sb0, sb1, acc);
  const int base = b * DT;
  // phase 1: acc = (acc + rs_self) * dinv
  for (int idx = t; idx < DT * 4; idx += 1024) {
    const int node = idx >> 2, sub = idx & 3;
    const int i = base + node;
    if (i < n) {
      float* arow = acc + node * AP + sub * 4;
      const __half2* rp = (const __half2*)(rs + (size_t)i * FH + sub * 4);
      const float2 r0 = __half22float2(rp[0]);
      const float2 r1 = __half22float2(rp[1]);
      const float d = dinv[i];
      arow[0] = (arow[0] + r0.x) * d;
      arow[1] = (arow[1] + r0.y) * d;
      arow[2] = (arow[2] + r1.x) * d;
      arow[3] = (arow[3] + r1.y) * d;
    }
  }
  __syncthreads();
  // overlay W2/b2 into the (now dead) stage buffer
  float* w2s = (float*)sb0;  // FH*FOUT + FOUT floats = 2.7 KiB < 16 KiB
  for (int idx = t; idx < FH * FOUT + FOUT; idx += 1024)
    w2s[idx] = (idx < FH * FOUT) ? W2[idx] : b2[idx - FH * FOUT];
  __syncthreads();
  // phase 2: per-node 16->40 matvec + log_softmax (16 waves round-robin)
  const int lane = t & 63, wv = t >> 6;
  for (int nd = wv; nd < DT; nd += 16) {
    const int i = base + nd;
    if (i >= n) continue;
    float hv = (lane < FOUT) ? w2s[FH * FOUT + lane] : 0.f;
#pragma unroll
    for (int kk = 0; kk < 16; ++kk) {
      const float a = acc[nd * AP + kk];
      if (lane < FOUT) hv += a * w2s[kk * FOUT + lane];
    }
    float m = (lane < FOUT) ? hv : -INFINITY;
#pragma unroll
    for (int d = 1; d < 64; d <<= 1) m = fmaxf(m, __shfl_xor(m, d));
    float ex = (lane < FOUT) ? expf(hv - m) : 0.f;
#pragma unroll
    for (int d = 1; d < 64; d <<= 1) ex += __shfl_xor(ex, d);
    if (lane < FOUT) out[(size_t)i * FOUT + lane] = hv - m - logf(ex);
  }
}

// ---------------- launch ----------------
extern "C" void kernel_launch(void* const* d_in, const int* in_sizes, int n_in,
                              void* d_out, int out_size, void* d_ws, size_t ws_size,
                              hipStream_t stream) {
  const float* x  = (const float*)d_in[0];
  const int*   ei = (const int*)d_in[1];
  const float* W1 = (const float*)d_in[2];
  const float* b1 = (const float*)d_in[3];
  const float* W2 = (const float*)d_in[4];
  const float* b2 = (const float*)d_in[5];
  float* out = (float*)d_out;

  const int n = in_sizes[0] / FIN;
  const int E = in_sizes[1] / 2;
  const int* src = ei;
  const int* dst = ei + E;
  const int NB  = (n + DT - 1) / DT;        // dst tiles (224)
  const int NTS = (n + SUB - 1) / SUB;      // src subtiles (196)
  const size_t padRows = (size_t)NTS * SUB; // padded table rows

  char* ws = (char*)d_ws;
  size_t o = 0;
  auto alloc = [&](size_t bytes) {
    void* p = ws + o;
    o = (o + bytes + 255) & ~(size_t)255;
    return p;
  };
  unsigned* bcnt = (unsigned*)alloc((size_t)(NB + 1) * 4);
  unsigned* boff = (unsigned*)alloc((size_t)(NB + 1) * 4);
  unsigned* bcur = (unsigned*)alloc((size_t)NB * 4);
  float*    dinv = (float*)alloc((size_t)n * 4);
  unsigned* bins = (unsigned*)alloc((size_t)E * 4);
  unsigned* out2 = (unsigned*)alloc((size_t)E * 4);
  unsigned* off2 = (unsigned*)alloc((size_t)NB * (NTS + 1) * 4);
  __half*   hs1  = (__half*)alloc(padRows * FH * 2);
  __half*   rsb  = (__half*)alloc(padRows * FH * 2);

  hipMemsetAsync(bcnt, 0, (size_t)(NB + 1) * 4, stream);

  histA_k<<<(E + HCHUNK - 1) / HCHUNK, 256, 0, stream>>>(dst, E, NB, bcnt);
  scanB_k<<<1, 1024, 0, stream>>>(bcnt, NB, boff, bcur);
  bin_k<<<(E + BCHUNK - 1) / BCHUNK, 256, 0, stream>>>(src, dst, E, NB, bcur, bins);
  deg_k<<<NB, 512, 0, stream>>>(boff, bins, n, dinv);
  bin2_k<<<NB, 1024, 0, stream>>>(boff, bins, NTS, out2, off2);

  gemm1_k<<<(n + 255) / 256, 256, 0, stream>>>(x, W1, dinv, n, hs1);
  gath1_k<<<NB, 1024, 0, stream>>>(hs1, boff, out2, off2, NTS, dinv, b1, n, rsb);
  gath2_k<<<NB, 1024, 0, stream>>>(rsb, boff, out2, off2, NTS, dinv, W2, b2, n, out);
}